// Round 4
// baseline (980.402 us; speedup 1.0000x reference)
//
#include <hip/hip_runtime.h>
#include <hip/hip_bf16.h>

typedef __bf16 bf16;
typedef __bf16 bf16x8 __attribute__((ext_vector_type(8)));
typedef __bf16 bf16x4 __attribute__((ext_vector_type(4)));
typedef float  f32x4  __attribute__((ext_vector_type(4)));

#define GLD_LDS(g, l)                                                        \
  __builtin_amdgcn_global_load_lds(                                          \
      (const __attribute__((address_space(1))) void*)(g),                    \
      (__attribute__((address_space(3))) void*)(l), 16, 0, 0)

#define BAR()   asm volatile("s_barrier" ::: "memory")
#define WLG()   asm volatile("s_waitcnt lgkmcnt(0)" ::: "memory")
#define WVM0()  asm volatile("s_waitcnt vmcnt(0)" ::: "memory")

// ---------------------------------------------------------------------------
// gemm256 v2: 256x256 tile, BK=32, 8 waves (2Mx4N, wave tile 128x64),
// LDS 64 KiB (A dbuf 2x16K @0, B dbuf 2x16K @32768) -> 2 blocks/CU.
// ONE barrier per K-tile; cross-block wave overlap replaces phase pipelining.
// Swizzle: LDS row stride 64 B; slot_byte = fq*16 ^ (((row>>1)&3)<<4).
//   Read side: row = 16*i + fr so (row>>1)&3 == (fr>>1)&3 (lane-constant).
//   Write side: linear gld_lds dest; per-lane global source k-chunk
//   pre-swizzled: c = (lane&3) ^ ((lane>>3)&3)  (involution, rule #21).
// Ledger: during tile T (reading buf T&1) stage tile T+1 into buf ~T&1,
//   whose last reads finished before the previous boundary barrier.
//   WLG drains own ds_reads, WVM0 drains staging, then BAR. Safe.
// C = A (MxK rm) * B^T (B NxK rm) + bias, fp32.  M,N %256==0, K%32==0.
// ---------------------------------------------------------------------------
__global__ __launch_bounds__(512, 4)
void gemm256(const bf16* __restrict__ A, const bf16* __restrict__ B,
             float* __restrict__ C, const float* __restrict__ bias_p,
             int M, int N, int K) {
  __shared__ char lds[65536];
  const int tid  = threadIdx.x;
  const int lane = tid & 63, wave = tid >> 6;
  const int wm = wave >> 2, wn = wave & 3;       // 2 x 4 waves
  const int fr = lane & 15, fq = lane >> 4;

  // XCD-aware block swizzle (nwg divisible by 8)
  const int nwg = gridDim.x;
  const int bid = blockIdx.x;
  const int swz = (bid & 7) * (nwg >> 3) + (bid >> 3);
  const int gx  = N >> 8;
  const int row0 = (swz / gx) << 8, col0 = (swz % gx) << 8;

  // staging source bases (pre-swizzled k-chunk)
  const int srow = wave * 16 + (lane >> 2);              // row within 128-half
  const int sk   = ((lane & 3) ^ ((lane >> 3) & 3)) * 8; // elems
  const bf16* Asrc = A + (size_t)(row0 + srow) * K + sk;
  const bf16* Bsrc = B + (size_t)(col0 + srow) * K + sk;
  char* ldsb = lds;

  // stage full K-tile t (A 2 halves + B 2 halves = 4 gld_lds)
#define STG(t)                                                               \
  do {                                                                       \
    const int _p = ((t) & 1) * 16384;                                        \
    const size_t _k = (size_t)(t) * 32;                                      \
    GLD_LDS(Asrc + _k,                   ldsb + _p + wave * 1024);           \
    GLD_LDS(Asrc + (size_t)128 * K + _k, ldsb + _p + 8192 + wave * 1024);    \
    GLD_LDS(Bsrc + _k,                   ldsb + 32768 + _p + wave * 1024);   \
    GLD_LDS(Bsrc + (size_t)128 * K + _k, ldsb + 32768 + _p + 8192 + wave * 1024); \
  } while (0)

  // loop-invariant read bases (swizzle term lane-constant)
  const int slot = (fq * 16) ^ (((fr >> 1) & 3) << 4);
  const char* Abase = ldsb + wm * 8192 + fr * 64 + slot;
  const char* Bbase = ldsb + 32768 + wn * 4096 + fr * 64 + slot;

  f32x4 acc[8][4] = {};

  // prologue
  STG(0);
  WVM0(); BAR();

  const int NT = K >> 5;
  for (int T = 0; T < NT; ++T) {
    if (T + 1 < NT) STG(T + 1);

    const char* Ab = Abase + (T & 1) * 16384;
    const char* Bb = Bbase + (T & 1) * 16384;
    bf16x8 bg[4], af[8];
#pragma unroll
    for (int n = 0; n < 4; ++n) bg[n] = *(const bf16x8*)(Bb + n * 1024);
#pragma unroll
    for (int m = 0; m < 8; ++m) af[m] = *(const bf16x8*)(Ab + m * 1024);

#pragma unroll
    for (int m = 0; m < 8; ++m)
#pragma unroll
      for (int n = 0; n < 4; ++n)
        acc[m][n] = __builtin_amdgcn_mfma_f32_16x16x32_bf16(af[m], bg[n],
                                                            acc[m][n], 0, 0, 0);
    WLG();   // own ds_reads retired before next tile's writes can land
    WVM0();  // staged tile T+1 landed
    BAR();
  }

  const float bias = bias_p[0];
#pragma unroll
  for (int m = 0; m < 8; ++m) {
#pragma unroll
    for (int n = 0; n < 4; ++n) {
      const int r = row0 + wm * 128 + m * 16 + fq * 4;
      const int c = col0 + wn * 64 + n * 16 + fr;
#pragma unroll
      for (int j = 0; j < 4; ++j)
        C[(size_t)(r + j) * N + c] = acc[m][n][j] + bias;
    }
  }
#undef STG
}

// ---------------------------------------------------------------------------
// m97-structure 128x128 GEMM (small XW = X*W^T, bf16 out)
// ---------------------------------------------------------------------------
__global__ void gemm_bt(const bf16* __restrict__ A, const bf16* __restrict__ B,
                        bf16* __restrict__ Cb, int M, int N, int K) {
  __shared__ bf16 As[128 * 32];
  __shared__ bf16 Bs[128 * 32];
  const int tid  = threadIdx.x;
  const int lane = tid & 63;
  const int wave = tid >> 6;
  const int wr = wave >> 1, wc = wave & 1;
  const int fr = lane & 15, fq = lane >> 4;
  const int row0 = blockIdx.y * 128, col0 = blockIdx.x * 128;

  f32x4 acc[4][4] = {};
  const int c0 = tid, c1 = 256 + tid;
  const bf16* Ag0 = A + (size_t)(row0 + (c0 >> 2)) * K + (c0 & 3) * 8;
  const bf16* Ag1 = A + (size_t)(row0 + (c1 >> 2)) * K + (c1 & 3) * 8;
  const bf16* Bg0 = B + (size_t)(col0 + (c0 >> 2)) * K + (c0 & 3) * 8;
  const bf16* Bg1 = B + (size_t)(col0 + (c1 >> 2)) * K + (c1 & 3) * 8;
  bf16* Al0 = As + (wave * 64) * 8;
  bf16* Al1 = As + (256 + wave * 64) * 8;
  bf16* Bl0 = Bs + (wave * 64) * 8;
  bf16* Bl1 = Bs + (256 + wave * 64) * 8;

  for (int k0 = 0; k0 < K; k0 += 32) {
    GLD_LDS(Ag0 + k0, Al0);
    GLD_LDS(Ag1 + k0, Al1);
    GLD_LDS(Bg0 + k0, Bl0);
    GLD_LDS(Bg1 + k0, Bl1);
    __syncthreads();
    bf16x8 af[4], bgf[4];
#pragma unroll
    for (int m = 0; m < 4; ++m)
      af[m] = *(const bf16x8*)&As[(wr * 64 + m * 16 + fr) * 32 + fq * 8];
#pragma unroll
    for (int n = 0; n < 4; ++n)
      bgf[n] = *(const bf16x8*)&Bs[(wc * 64 + n * 16 + fr) * 32 + fq * 8];
#pragma unroll
    for (int m = 0; m < 4; ++m)
#pragma unroll
      for (int n = 0; n < 4; ++n)
        acc[m][n] = __builtin_amdgcn_mfma_f32_16x16x32_bf16(af[m], bgf[n],
                                                            acc[m][n], 0, 0, 0);
    __syncthreads();
  }
#pragma unroll
  for (int m = 0; m < 4; ++m)
#pragma unroll
    for (int n = 0; n < 4; ++n) {
      const int r  = row0 + wr * 64 + m * 16 + fq * 4;
      const int cc = col0 + wc * 64 + n * 16 + fr;
#pragma unroll
      for (int j = 0; j < 4; ++j)
        Cb[(size_t)(r + j) * N + cc] = (bf16)acc[m][n][j];
    }
}

__global__ void cvt_f32_bf16(const float* __restrict__ in, bf16* __restrict__ out,
                             int n4) {
  int i = blockIdx.x * blockDim.x + threadIdx.x;
  if (i >= n4) return;
  const float4 v = ((const float4*)in)[i];
  bf16x4 o;
  o[0] = (bf16)v.x; o[1] = (bf16)v.y; o[2] = (bf16)v.z; o[3] = (bf16)v.w;
  ((bf16x4*)out)[i] = o;
}

__global__ void transpose_cvt_w(const float* __restrict__ W, bf16* __restrict__ Wt) {
  __shared__ float s[32][33];
  const int tx = threadIdx.x & 31;
  const int ty = threadIdx.x >> 5;
  const int n0 = blockIdx.x * 32;
  const int k0 = blockIdx.y * 32;
#pragma unroll
  for (int p = 0; p < 4; ++p)
    s[ty + p * 8][tx] = W[(size_t)(k0 + ty + p * 8) * 1024 + n0 + tx];
  __syncthreads();
#pragma unroll
  for (int p = 0; p < 4; ++p)
    Wt[(size_t)(n0 + ty + p * 8) * 1024 + k0 + tx] = (bf16)s[tx][ty + p * 8];
}

extern "C" void kernel_launch(void* const* d_in, const int* in_sizes, int n_in,
                              void* d_out, int out_size, void* d_ws, size_t ws_size,
                              hipStream_t stream) {
  const float* X = (const float*)d_in[0];   // (8192, 1024)
  const float* W = (const float*)d_in[1];   // (1024, 1024)
  const float* b = (const float*)d_in[2];   // (1,)
  float* out = (float*)d_out;               // (8192, 8192)

  const int Nn = 8192, D = 1024;
  char* ws = (char*)d_ws;
  bf16* Xb  = (bf16*)(ws);
  bf16* XWb = (bf16*)(ws + (size_t)16 * 1024 * 1024);
  bf16* Wt  = (bf16*)(ws + (size_t)32 * 1024 * 1024);

  cvt_f32_bf16<<<(Nn * D / 4 + 255) / 256, 256, 0, stream>>>(X, Xb, Nn * D / 4);
  transpose_cvt_w<<<dim3(D / 32, D / 32), 256, 0, stream>>>(W, Wt);
  gemm_bt<<<dim3(D / 128, Nn / 128), 256, 0, stream>>>(Xb, Wt, XWb, Nn, D, D);
  gemm256<<<(Nn / 256) * (Nn / 256), 512, 0, stream>>>(XWb, Xb, out, b,
                                                       Nn, Nn, D);
}

// Round 5
// 197.967 us; speedup vs baseline: 4.9524x; 4.9524x over previous
//
#include <hip/hip_runtime.h>
#include <hip/hip_bf16.h>

typedef __bf16 bf16;
typedef __bf16 bf16x8 __attribute__((ext_vector_type(8)));
typedef __bf16 bf16x4 __attribute__((ext_vector_type(4)));
typedef float  f32x4  __attribute__((ext_vector_type(4)));

#define GLD_LDS(g, l)                                                        \
  __builtin_amdgcn_global_load_lds(                                          \
      (const __attribute__((address_space(1))) void*)(g),                    \
      (__attribute__((address_space(3))) void*)(l), 16, 0, 0)

#define SB()    __builtin_amdgcn_s_barrier()
#define LG0()   asm volatile("s_waitcnt lgkmcnt(0)" ::: "memory")
#define WVM2()  asm volatile("s_waitcnt vmcnt(2)" ::: "memory")
#define WVM0()  asm volatile("s_waitcnt vmcnt(0)" ::: "memory")
#define PRIO1() __builtin_amdgcn_s_setprio(1)
#define PRIO0() __builtin_amdgcn_s_setprio(0)

// ---------------------------------------------------------------------------
// 256x256 tile, BK=64, 8 waves (2Mx4N), 8-phase m201-template schedule.
// BUILTIN s_barrier (no memory clobber) so the scheduler may interleave
// next-phase ds_reads / stages with the current MFMA cluster; correctness:
//  - lgkmcnt(0) at every read-phase => each wave's reads complete before its
//    barrier arrival => 1-barrier-later LDS overwrite is race-free;
//  - counted vmcnt(2) at ph4/ph8 (asm, memory) anchors the staging ledger:
//    at each wait <=10 loads in flight, all but newest half-tile (2) drain;
//  - compiler tracks af/bg load->MFMA deps (plain C ds_reads).
// Staging: 1 half-tile (2 gld_lds) per phase:
//  ph1 T+1.Ah1 | ph2 T+1.Bh0 | ph3 T+1.Bh1 | ph4 T+2.Ah0 +vmcnt(2)
//  ph5 T+2.Ah1 | ph6 T+2.Bh0 | ph7 T+2.Bh1 | ph8 T+3.Ah0 +vmcnt(2)
//  (prologue: T0 all 4 halves + T1.Ah0, vmcnt(2); tails drain vmcnt(0))
// Buffer-freedom: every overwrite >=1 barrier after that region's last read.
// LDS 128 KiB: A dbuf @0 (2x32KB), B dbuf @65536. XOR swizzle as R3
// (byte bits 4-6 ^= row&7; write side pre-swizzles the global k-chunk).
// C = A (MxK rm) * B^T (B NxK rm) + bias, fp32.  M,N %256==0, K%128==0.
// ---------------------------------------------------------------------------
__global__ __launch_bounds__(512, 2)
void gemm256(const bf16* __restrict__ A, const bf16* __restrict__ B,
             float* __restrict__ C, const float* __restrict__ bias_p,
             int M, int N, int K) {
  extern __shared__ bf16 lds[];
  const int tid  = threadIdx.x;
  const int lane = tid & 63, wave = tid >> 6;
  const int wm = wave >> 2, wn = wave & 3;       // 2 x 4 waves
  const int fr = lane & 15, fq = lane >> 4;
  const int xm = (fr & 7) << 4;
  const int kx0 = (fq * 16) ^ xm;
  const int kx1 = (fq * 16 + 64) ^ xm;

  // XCD-aware block swizzle (nwg divisible by 8)
  const int nwg = gridDim.x;
  const int bid = blockIdx.x;
  const int swz = (bid & 7) * (nwg >> 3) + (bid >> 3);
  const int gx  = N >> 8;
  const int row0 = (swz / gx) << 8, col0 = (swz % gx) << 8;

  // staging source (pre-swizzled k-chunk)
  const int srow = wave * 8 + (lane >> 3);
  const int scol = ((lane & 7) ^ (lane >> 3)) * 8;
  const bf16* Agl = A + (size_t)(row0 + srow) * K + scol;
  const bf16* Bgl = B + (size_t)(col0 + srow) * K + scol;

  // stage half-tile h of K-tile t; tb = 0 (A) or 32768 (B), elem offsets
#define STG(gl, tb, t, h)                                                    \
  do {                                                                       \
    const size_t _k = (size_t)(t) * 64;                                      \
    GLD_LDS((gl) + (size_t)((h) * 128) * K + _k,                             \
            lds + (tb) + ((t) & 1) * 16384 + (h) * 8192 + wave * 512);       \
    GLD_LDS((gl) + (size_t)((h) * 128 + 64) * K + _k,                        \
            lds + (tb) + ((t) & 1) * 16384 + (h) * 8192 + 4096 + wave * 512);\
  } while (0)

  const char* ldsc = (const char*)lds;
  const char* Ab0 = ldsc + wm * 16384 + fr * 128 + kx0;
  const char* Ab1 = ldsc + wm * 16384 + fr * 128 + kx1;
  const char* Bb0 = ldsc + 65536 + wn * 8192 + fr * 128 + kx0;
  const char* Bb1 = ldsc + 65536 + wn * 8192 + fr * 128 + kx1;

  f32x4  acc[8][4] = {};
  bf16x8 af[4][2];
  bf16x8 bg[4][2];

#define LDA(mg, p)                                                           \
  do {                                                                       \
    _Pragma("unroll") for (int m_ = 0; m_ < 4; ++m_) {                       \
      af[m_][0] = *(const bf16x8*)(Ab0 + (p) * 32768 + ((mg) * 4 + m_) * 2048);\
      af[m_][1] = *(const bf16x8*)(Ab1 + (p) * 32768 + ((mg) * 4 + m_) * 2048);\
    }                                                                        \
  } while (0)

#define LDB(np, p)                                                           \
  do {                                                                       \
    _Pragma("unroll") for (int n_ = 0; n_ < 2; ++n_) {                       \
      bg[(np) * 2 + n_][0] =                                                 \
          *(const bf16x8*)(Bb0 + (p) * 32768 + ((np) * 2 + n_) * 2048);      \
      bg[(np) * 2 + n_][1] =                                                 \
          *(const bf16x8*)(Bb1 + (p) * 32768 + ((np) * 2 + n_) * 2048);      \
    }                                                                        \
  } while (0)

#define MM(mg, np)                                                           \
  do {                                                                       \
    _Pragma("unroll") for (int kk_ = 0; kk_ < 2; ++kk_)                      \
      _Pragma("unroll") for (int m_ = 0; m_ < 4; ++m_)                       \
        _Pragma("unroll") for (int n_ = 0; n_ < 2; ++n_)                     \
          acc[(mg) * 4 + m_][(np) * 2 + n_] =                                \
              __builtin_amdgcn_mfma_f32_16x16x32_bf16(                       \
                  af[m_][kk_], bg[(np) * 2 + n_][kk_],                       \
                  acc[(mg) * 4 + m_][(np) * 2 + n_], 0, 0, 0);               \
  } while (0)

  // prologue: T0 (4 halves) + T1.Ah0 => 10 loads; keep newest 2 in flight
  STG(Agl, 0, 0, 0); STG(Agl, 0, 0, 1);
  STG(Bgl, 32768, 0, 0); STG(Bgl, 32768, 0, 1);
  STG(Agl, 0, 1, 0);
  WVM2(); SB();

  const int NT = K >> 6;
  for (int T = 0; T < NT; T += 2) {
    const bool s2 = (T + 2 < NT), s3 = (T + 3 < NT);
    // ph1
    LDA(0, 0); LDB(0, 0);
    STG(Agl, 0, T + 1, 1);
    SB(); LG0(); PRIO1(); MM(0, 0); PRIO0(); SB();
    // ph2
    LDB(1, 0);
    STG(Bgl, 32768, T + 1, 0);
    SB(); LG0(); PRIO1(); MM(0, 1); PRIO0(); SB();
    // ph3
    LDA(1, 0);
    STG(Bgl, 32768, T + 1, 1);
    SB(); LG0(); PRIO1(); MM(1, 0); PRIO0(); SB();
    // ph4 (no reads)
    if (s2) STG(Agl, 0, T + 2, 0);
    SB(); PRIO1(); MM(1, 1); PRIO0();
    if (s2) { WVM2(); } else { WVM0(); }
    SB();
    // ph5
    LDA(0, 1); LDB(0, 1);
    if (s2) STG(Agl, 0, T + 2, 1);
    SB(); LG0(); PRIO1(); MM(0, 0); PRIO0(); SB();
    // ph6
    LDB(1, 1);
    if (s2) STG(Bgl, 32768, T + 2, 0);
    SB(); LG0(); PRIO1(); MM(0, 1); PRIO0(); SB();
    // ph7
    LDA(1, 1);
    if (s2) STG(Bgl, 32768, T + 2, 1);
    SB(); LG0(); PRIO1(); MM(1, 0); PRIO0(); SB();
    // ph8 (no reads)
    if (s3) STG(Agl, 0, T + 3, 0);
    SB(); PRIO1(); MM(1, 1); PRIO0();
    if (s3) { WVM2(); } else { WVM0(); }
    SB();
  }

  const float bias = bias_p[0];
#pragma unroll
  for (int m = 0; m < 8; ++m) {
#pragma unroll
    for (int n = 0; n < 4; ++n) {
      const int r = row0 + wm * 128 + m * 16 + fq * 4;
      const int c = col0 + wn * 64 + n * 16 + fr;
#pragma unroll
      for (int j = 0; j < 4; ++j)
        C[(size_t)(r + j) * N + c] = acc[m][n][j] + bias;
    }
  }
#undef STG
#undef LDA
#undef LDB
#undef MM
}

// ---------------------------------------------------------------------------
// m97-structure 128x128 GEMM (small XW = X*W^T, bf16 out)
// ---------------------------------------------------------------------------
__global__ void gemm_bt(const bf16* __restrict__ A, const bf16* __restrict__ B,
                        bf16* __restrict__ Cb, int M, int N, int K) {
  __shared__ bf16 As[128 * 32];
  __shared__ bf16 Bs[128 * 32];
  const int tid  = threadIdx.x;
  const int lane = tid & 63;
  const int wave = tid >> 6;
  const int wr = wave >> 1, wc = wave & 1;
  const int fr = lane & 15, fq = lane >> 4;
  const int row0 = blockIdx.y * 128, col0 = blockIdx.x * 128;

  f32x4 acc[4][4] = {};
  const int c0 = tid, c1 = 256 + tid;
  const bf16* Ag0 = A + (size_t)(row0 + (c0 >> 2)) * K + (c0 & 3) * 8;
  const bf16* Ag1 = A + (size_t)(row0 + (c1 >> 2)) * K + (c1 & 3) * 8;
  const bf16* Bg0 = B + (size_t)(col0 + (c0 >> 2)) * K + (c0 & 3) * 8;
  const bf16* Bg1 = B + (size_t)(col0 + (c1 >> 2)) * K + (c1 & 3) * 8;
  bf16* Al0 = As + (wave * 64) * 8;
  bf16* Al1 = As + (256 + wave * 64) * 8;
  bf16* Bl0 = Bs + (wave * 64) * 8;
  bf16* Bl1 = Bs + (256 + wave * 64) * 8;

  for (int k0 = 0; k0 < K; k0 += 32) {
    GLD_LDS(Ag0 + k0, Al0);
    GLD_LDS(Ag1 + k0, Al1);
    GLD_LDS(Bg0 + k0, Bl0);
    GLD_LDS(Bg1 + k0, Bl1);
    __syncthreads();
    bf16x8 af[4], bgf[4];
#pragma unroll
    for (int m = 0; m < 4; ++m)
      af[m] = *(const bf16x8*)&As[(wr * 64 + m * 16 + fr) * 32 + fq * 8];
#pragma unroll
    for (int n = 0; n < 4; ++n)
      bgf[n] = *(const bf16x8*)&Bs[(wc * 64 + n * 16 + fr) * 32 + fq * 8];
#pragma unroll
    for (int m = 0; m < 4; ++m)
#pragma unroll
      for (int n = 0; n < 4; ++n)
        acc[m][n] = __builtin_amdgcn_mfma_f32_16x16x32_bf16(af[m], bgf[n],
                                                            acc[m][n], 0, 0, 0);
    __syncthreads();
  }
#pragma unroll
  for (int m = 0; m < 4; ++m)
#pragma unroll
    for (int n = 0; n < 4; ++n) {
      const int r  = row0 + wr * 64 + m * 16 + fq * 4;
      const int cc = col0 + wc * 64 + n * 16 + fr;
#pragma unroll
      for (int j = 0; j < 4; ++j)
        Cb[(size_t)(r + j) * N + cc] = (bf16)acc[m][n][j];
    }
}

__global__ void cvt_f32_bf16(const float* __restrict__ in, bf16* __restrict__ out,
                             int n4) {
  int i = blockIdx.x * blockDim.x + threadIdx.x;
  if (i >= n4) return;
  const float4 v = ((const float4*)in)[i];
  bf16x4 o;
  o[0] = (bf16)v.x; o[1] = (bf16)v.y; o[2] = (bf16)v.z; o[3] = (bf16)v.w;
  ((bf16x4*)out)[i] = o;
}

__global__ void transpose_cvt_w(const float* __restrict__ W, bf16* __restrict__ Wt) {
  __shared__ float s[32][33];
  const int tx = threadIdx.x & 31;
  const int ty = threadIdx.x >> 5;
  const int n0 = blockIdx.x * 32;
  const int k0 = blockIdx.y * 32;
#pragma unroll
  for (int p = 0; p < 4; ++p)
    s[ty + p * 8][tx] = W[(size_t)(k0 + ty + p * 8) * 1024 + n0 + tx];
  __syncthreads();
#pragma unroll
  for (int p = 0; p < 4; ++p)
    Wt[(size_t)(n0 + ty + p * 8) * 1024 + k0 + tx] = (bf16)s[tx][ty + p * 8];
}

extern "C" void kernel_launch(void* const* d_in, const int* in_sizes, int n_in,
                              void* d_out, int out_size, void* d_ws, size_t ws_size,
                              hipStream_t stream) {
  const float* X = (const float*)d_in[0];   // (8192, 1024)
  const float* W = (const float*)d_in[1];   // (1024, 1024)
  const float* b = (const float*)d_in[2];   // (1,)
  float* out = (float*)d_out;               // (8192, 8192)

  const int Nn = 8192, D = 1024;
  char* ws = (char*)d_ws;
  bf16* Xb  = (bf16*)(ws);
  bf16* XWb = (bf16*)(ws + (size_t)16 * 1024 * 1024);
  bf16* Wt  = (bf16*)(ws + (size_t)32 * 1024 * 1024);

  cvt_f32_bf16<<<(Nn * D / 4 + 255) / 256, 256, 0, stream>>>(X, Xb, Nn * D / 4);
  transpose_cvt_w<<<dim3(D / 32, D / 32), 256, 0, stream>>>(W, Wt);
  gemm_bt<<<dim3(D / 128, Nn / 128), 256, 0, stream>>>(Xb, Wt, XWb, Nn, D, D);
  gemm256<<<(Nn / 256) * (Nn / 256), 512, 131072, stream>>>(XWb, Xb, out, b,
                                                            Nn, Nn, D);
}